// Round 3
// baseline (3059.345 us; speedup 1.0000x reference)
//
#include <hip/hip_runtime.h>
#include <math.h>

#define Cdim   256
#define Ssp    8192      // D*H*W = 8*32*32
#define Npts   65536     // B * Ssp
#define NCODES 1024
#define BETA   0.25f

// ---------------- embed norms ----------------
__global__ __launch_bounds__(256) void enorm_kernel(const float* __restrict__ embed,
                                                    float* __restrict__ enorm) {
    int j = blockIdx.x * 256 + threadIdx.x;
    if (j >= NCODES) return;
    const float4* row = reinterpret_cast<const float4*>(embed + (size_t)j * Cdim);
    float s = 0.f;
#pragma unroll 8
    for (int c4 = 0; c4 < Cdim / 4; ++c4) {
        float4 v = row[c4];
        s += v.x * v.x + v.y * v.y + v.z * v.z + v.w * v.w;
    }
    enorm[j] = s;
}

// ---------------- main kernel: 1 point per lane, z register-resident ----------------
// 256 threads/block, 256 blocks (one per CU). Each lane holds its point's full
// z row in 256 VGPRs (1 wave/SIMD). Code rows are wave-uniform -> s_load into
// SGPRs; v_fmac uses the SGPR operand directly. Zero LDS traffic.
__global__ __launch_bounds__(256, 1) void vq_dist(const float* __restrict__ z,
                                                  const float* __restrict__ embed,
                                                  const float* __restrict__ enorm,
                                                  float* __restrict__ out_zq,
                                                  float* __restrict__ out_idx,
                                                  float* __restrict__ loss_acc,
                                                  float* __restrict__ counts) {
    const int n = blockIdx.x * 256 + threadIdx.x;   // point id
    const int b = n >> 13;
    const int s = n & 8191;
    const float* zb = z + (size_t)b * ((size_t)Cdim * Ssp) + s;

    // ---- load z row into registers (coalesced across lanes per c) ----
    float zr[Cdim];
#pragma unroll
    for (int c = 0; c < Cdim; ++c) zr[c] = zb[(size_t)c * Ssp];

    // ---- ||z||^2 with the same summation tree as the round-2 passing kernel:
    //      4 sequential 64-chunks combined ((q0+q1)+q2)+q3 ----
    float qp[4];
#pragma unroll
    for (int qq = 0; qq < 4; ++qq) {
        float sacc = 0.f;
#pragma unroll
        for (int u = 0; u < 64; ++u) { float v = zr[qq * 64 + u]; sacc += v * v; }
        qp[qq] = sacc;
    }
    const float zn = ((qp[0] + qp[1]) + qp[2]) + qp[3];

    // ---- argmin over all codes; 4 codes at a time = 4 independent FMA chains
    //      (covers dep latency at 1 wave/SIMD), each chain strictly c-sequential
    //      (identical fl() sequence to round 2) ----
    float bestv = 3.0e38f;
    int   besti = 0;
#pragma unroll 1
    for (int j0 = 0; j0 < NCODES; j0 += 4) {
        const float* e = embed + (size_t)j0 * Cdim;   // uniform -> scalar loads
        float a0 = 0.f, a1 = 0.f, a2 = 0.f, a3 = 0.f;
#pragma unroll
        for (int c = 0; c < Cdim; ++c) {
            const float zc = zr[c];
            a0 += zc * e[c];
            a1 += zc * e[Cdim + c];
            a2 += zc * e[2 * Cdim + c];
            a3 += zc * e[3 * Cdim + c];
        }
        // reference rounding: fl( fl(zn+en) - fl(2*dot) ); 2*acc exact
        float k1, sc;
        k1 = zn + enorm[j0 + 0]; sc = k1 - 2.0f * a0; if (sc < bestv) { bestv = sc; besti = j0 + 0; }
        k1 = zn + enorm[j0 + 1]; sc = k1 - 2.0f * a1; if (sc < bestv) { bestv = sc; besti = j0 + 1; }
        k1 = zn + enorm[j0 + 2]; sc = k1 - 2.0f * a2; if (sc < bestv) { bestv = sc; besti = j0 + 2; }
        k1 = zn + enorm[j0 + 3]; sc = k1 - 2.0f * a3; if (sc < bestv) { bestv = sc; besti = j0 + 3; }
    }

    // ---- outputs: index (as float), histogram, z_q, commitment loss ----
    out_idx[n] = (float)besti;
    atomicAdd(&counts[besti], 1.0f);

    const float4* er4 = reinterpret_cast<const float4*>(embed + (size_t)besti * Cdim);
    float* ob = out_zq + (size_t)b * ((size_t)Cdim * Ssp) + s;
    float lsum = 0.f;
#pragma unroll 4
    for (int c4 = 0; c4 < Cdim / 4; ++c4) {
        float4 ev = er4[c4];                 // per-lane gather, L2-hot (embed = 1MB)
        const int c = c4 * 4;
        ob[(size_t)(c + 0) * Ssp] = ev.x;    // coalesced across lanes
        ob[(size_t)(c + 1) * Ssp] = ev.y;
        ob[(size_t)(c + 2) * Ssp] = ev.z;
        ob[(size_t)(c + 3) * Ssp] = ev.w;
        float d0 = zr[c + 0] - ev.x, d1 = zr[c + 1] - ev.y;
        float d2 = zr[c + 2] - ev.z, d3 = zr[c + 3] - ev.w;
        lsum += d0 * d0 + d1 * d1 + d2 * d2 + d3 * d3;
    }
#pragma unroll
    for (int off = 32; off > 0; off >>= 1) lsum += __shfl_down(lsum, off, 64);
    if ((threadIdx.x & 63) == 0) atomicAdd(loss_acc, lsum);
}

// ---------------- finalize: loss + perplexity ----------------
__global__ __launch_bounds__(1024) void vq_final(const float* __restrict__ counts,
                                                 const float* __restrict__ loss_acc,
                                                 float* __restrict__ out_loss,
                                                 float* __restrict__ out_perp) {
    __shared__ float red[16];
    int t = threadIdx.x;
    float cnt = counts[t];
    float avg = cnt * (1.0f / (float)Npts);
    float term = avg * logf(avg + 1e-10f);
#pragma unroll
    for (int off = 32; off > 0; off >>= 1) term += __shfl_down(term, off, 64);
    if ((t & 63) == 0) red[t >> 6] = term;
    __syncthreads();
    if (t == 0) {
        float s = 0.f;
        for (int i = 0; i < 16; ++i) s += red[i];
        *out_perp = expf(-s);
        *out_loss = BETA * loss_acc[0] * (1.0f / 16777216.0f);  // mean over N*C
    }
}

extern "C" void kernel_launch(void* const* d_in, const int* in_sizes, int n_in,
                              void* d_out, int out_size, void* d_ws, size_t ws_size,
                              hipStream_t stream) {
    const float* z     = (const float*)d_in[0];
    const float* embed = (const float*)d_in[1];

    float* ws       = (float*)d_ws;
    float* loss_acc = ws;            // [0]
    float* counts   = ws + 64;       // [1024]
    float* enorm    = ws + 2048;     // [1024]

    float* out_zq   = (float*)d_out;                       // 16777216
    float* out_idx  = out_zq + (size_t)Npts * Cdim;        // 65536
    float* out_loss = out_idx + Npts;                      // 1
    float* out_perp = out_loss + 1;                        // 1

    hipMemsetAsync(d_ws, 0, 2048 * sizeof(float), stream); // loss + counts
    enorm_kernel<<<NCODES / 256, 256, 0, stream>>>(embed, enorm);
    vq_dist<<<Npts / 256, 256, 0, stream>>>(z, embed, enorm, out_zq, out_idx,
                                            loss_acc, counts);
    vq_final<<<1, 1024, 0, stream>>>(counts, loss_acc, out_loss, out_perp);
}

// Round 4
// 486.330 us; speedup vs baseline: 6.2907x; 6.2907x over previous
//
#include <hip/hip_runtime.h>
#include <math.h>

#define Cdim   256
#define Ssp    8192      // D*H*W = 8*32*32
#define Npts   65536     // B * Ssp
#define NCODES 1024
#define PTS    64        // points per block
#define CT     128       // codes per j-tile
#define KC     32        // c-chunk of embed staged per step
#define BETA   0.25f

// ---------------- embed norms ----------------
__global__ __launch_bounds__(256) void enorm_kernel(const float* __restrict__ embed,
                                                    float* __restrict__ enorm) {
    int j = blockIdx.x * 256 + threadIdx.x;
    if (j >= NCODES) return;
    const float4* row = reinterpret_cast<const float4*>(embed + (size_t)j * Cdim);
    float s = 0.f;
#pragma unroll 8
    for (int c4 = 0; c4 < Cdim / 4; ++c4) {
        float4 v = row[c4];
        s += v.x * v.x + v.y * v.y + v.z * v.z + v.w * v.w;
    }
    enorm[j] = s;
}

// ---------------- main fused kernel ----------------
// 64KB z-tile + 16KB c-major swizzled embed chunk = exactly 80KB -> 2 blocks/CU.
// Register tile 4 points x 8 codes: 3x ds_read_b128 per 32 FMA, bank-conflict-free.
// fl() sequence (per-code c-ascending dot, zn tree, score formula) is identical
// to the round-2 passing kernel -> bit-identical indices.
__global__ __launch_bounds__(256, 2) void vq_main(const float* __restrict__ z,
                                                  const float* __restrict__ embed,
                                                  const float* __restrict__ enorm,
                                                  float* __restrict__ out_zq,
                                                  float* __restrict__ out_idx,
                                                  float* __restrict__ loss_acc,
                                                  float* __restrict__ counts) {
    __shared__ __attribute__((aligned(16))) float smem[Cdim * PTS + KC * CT];
    float* zt = smem;                  // [256][64]  c-major, p fast
    float* et = smem + Cdim * PTS;     // [KC][CT]   c rows, j fast, XOR-swizzled

    const int t  = threadIdx.x;
    const int n0 = blockIdx.x * PTS;
    const int b  = n0 >> 13;           // n0 / 8192
    const int s0 = n0 & 8191;
    const float* zb = z + (size_t)b * Cdim * Ssp + s0;

    // ---- stage z tile: zt[c][p] = z[b][c][s0+p] ----
    {
        const int p4   = (t & 15) * 4;
        const int crow = t >> 4;
#pragma unroll
        for (int it = 0; it < 16; ++it) {
            int c = it * 16 + crow;
            float4 v = *reinterpret_cast<const float4*>(zb + (size_t)c * Ssp + p4);
            *reinterpret_cast<float4*>(&zt[c * PTS + p4]) = v;
        }
    }
    __syncthreads();

    // ---- per-point ||z||^2 partials (et used as scratch; overwritten later) ----
    {
        const int p = t & 63;
        const int qq = t >> 6;
        float sacc = 0.f;
#pragma unroll 8
        for (int c = qq * 64; c < qq * 64 + 64; ++c) {
            float v = zt[c * PTS + p];
            sacc += v * v;
        }
        et[qq * 64 + p] = sacc;
    }
    __syncthreads();

    const int pg = t & 15, jg = t >> 4;
    const int p0 = pg * 4;

    float zn[4];
#pragma unroll
    for (int i = 0; i < 4; ++i) {
        int p = p0 + i;
        zn[i] = ((et[p] + et[64 + p]) + et[128 + p]) + et[192 + p];
    }
    // (first __syncthreads of the chunk loop protects et before overwrite)

    float bestv[4] = {3.0e38f, 3.0e38f, 3.0e38f, 3.0e38f};
    int   besti[4] = {0, 0, 0, 0};

    // staging assignment: dj = code row (0..31, x4), q = c-quad (0..7)
    const int dj    = t >> 3;
    const int q     = t & 7;
    const int sw_st = (q & 3) << 3;    // XOR swizzle for writes (c>>2 == q)

    for (int jt = 0; jt < NCODES / CT; ++jt) {
        const int J0 = jt * CT;
        float acc[4][8];
#pragma unroll
        for (int i = 0; i < 4; ++i)
#pragma unroll
            for (int m = 0; m < 8; ++m) acc[i][m] = 0.f;

        for (int ks = 0; ks < Cdim / KC; ++ks) {
            const int cc0 = ks * KC;
            __syncthreads();   // readers of et done
            // ---- stage embed chunk transposed: et[c][ j ^ (((c>>2)&3)<<3) ] ----
#pragma unroll
            for (int i = 0; i < 4; ++i) {
                const int jrel = dj + 32 * i;
                const float4 v = *reinterpret_cast<const float4*>(
                    embed + (size_t)(J0 + jrel) * Cdim + cc0 + q * 4);
                const int c0 = q * 4;
                const int jsw = jrel ^ sw_st;
                et[(c0 + 0) * CT + jsw] = v.x;
                et[(c0 + 1) * CT + jsw] = v.y;
                et[(c0 + 2) * CT + jsw] = v.z;
                et[(c0 + 3) * CT + jsw] = v.w;
            }
            __syncthreads();
            // ---- 32 c-iters, each: 1 z b128 + 2 e b128 + 32 FMA ----
#pragma unroll 4
            for (int c = 0; c < KC; ++c) {
                const float4 zp = *reinterpret_cast<const float4*>(&zt[(cc0 + c) * PTS + p0]);
                const int jb = (jg * 8) ^ (((c >> 2) & 3) << 3);
                const float4 ea = *reinterpret_cast<const float4*>(&et[c * CT + jb]);
                const float4 eb = *reinterpret_cast<const float4*>(&et[c * CT + jb + 4]);
                const float zc[4] = {zp.x, zp.y, zp.z, zp.w};
                const float ec[8] = {ea.x, ea.y, ea.z, ea.w, eb.x, eb.y, eb.z, eb.w};
#pragma unroll
                for (int i = 0; i < 4; ++i)
#pragma unroll
                    for (int m = 0; m < 8; ++m)
                        acc[i][m] += zc[i] * ec[m];
            }
        }
        // ---- scores: fl( fl(zn+en) - 2*dot ), first-occurrence argmin ----
#pragma unroll
        for (int m = 0; m < 8; ++m) {
            const int cid = J0 + jg * 8 + m;
            const float en = enorm[cid];
#pragma unroll
            for (int i = 0; i < 4; ++i) {
                float k1 = zn[i] + en;
                float sc = k1 - 2.0f * acc[i][m];
                if (sc < bestv[i]) { bestv[i] = sc; besti[i] = cid; }
            }
        }
    }

    // ---- cross-thread argmin reduce (16 jg groups per point) ----
    __syncthreads();
    float* rv   = et;                       // 1024 floats
    int*   ri   = (int*)(et + 1024);        // 1024 ints
    int*   idxf = (int*)(et + 2048);        // 64 ints
#pragma unroll
    for (int i = 0; i < 4; ++i) {
        int p = p0 + i;
        rv[p * 16 + jg] = bestv[i];
        ri[p * 16 + jg] = besti[i];
    }
    __syncthreads();
    if (t < PTS) {
        int p = t;
        float bv = rv[p * 16]; int bi = ri[p * 16];
        for (int g = 1; g < 16; ++g) {
            float v = rv[p * 16 + g]; int ii = ri[p * 16 + g];
            if (v < bv || (v == bv && ii < bi)) { bv = v; bi = ii; }
        }
        idxf[p] = bi;
        out_idx[n0 + p] = (float)bi;        // indices as float
        atomicAdd(&counts[bi], 1.0f);
    }
    __syncthreads();

    // ---- epilogue: z_q write (coalesced over p) + commitment loss ----
    float lsum = 0.f;
    {
        const int p     = t & 63;
        const int cbase = t >> 6;
        const int myidx = idxf[p];
        const float4* erow4 = reinterpret_cast<const float4*>(embed + (size_t)myidx * Cdim);
        float* ob = out_zq + (size_t)b * Cdim * Ssp + s0 + p;
#pragma unroll 4
        for (int pass = 0; pass < 16; ++pass) {
            int c = cbase * 64 + pass * 4;
            float4 e = erow4[c >> 2];
            ob[(size_t)(c + 0) * Ssp] = e.x;
            ob[(size_t)(c + 1) * Ssp] = e.y;
            ob[(size_t)(c + 2) * Ssp] = e.z;
            ob[(size_t)(c + 3) * Ssp] = e.w;
            float d0 = zt[(c + 0) * PTS + p] - e.x;
            float d1 = zt[(c + 1) * PTS + p] - e.y;
            float d2 = zt[(c + 2) * PTS + p] - e.z;
            float d3 = zt[(c + 3) * PTS + p] - e.w;
            lsum += d0 * d0 + d1 * d1 + d2 * d2 + d3 * d3;
        }
    }
#pragma unroll
    for (int off = 32; off > 0; off >>= 1) lsum += __shfl_down(lsum, off, 64);
    if ((t & 63) == 0) atomicAdd(loss_acc, lsum);
}

// ---------------- finalize: loss + perplexity ----------------
__global__ __launch_bounds__(1024) void vq_final(const float* __restrict__ counts,
                                                 const float* __restrict__ loss_acc,
                                                 float* __restrict__ out_loss,
                                                 float* __restrict__ out_perp) {
    __shared__ float red[16];
    int t = threadIdx.x;
    float cnt = counts[t];
    float avg = cnt * (1.0f / (float)Npts);
    float term = avg * logf(avg + 1e-10f);
#pragma unroll
    for (int off = 32; off > 0; off >>= 1) term += __shfl_down(term, off, 64);
    if ((t & 63) == 0) red[t >> 6] = term;
    __syncthreads();
    if (t == 0) {
        float s = 0.f;
        for (int i = 0; i < 16; ++i) s += red[i];
        *out_perp = expf(-s);
        *out_loss = BETA * loss_acc[0] * (1.0f / 16777216.0f);  // mean over N*C
    }
}

extern "C" void kernel_launch(void* const* d_in, const int* in_sizes, int n_in,
                              void* d_out, int out_size, void* d_ws, size_t ws_size,
                              hipStream_t stream) {
    const float* z     = (const float*)d_in[0];
    const float* embed = (const float*)d_in[1];

    float* ws       = (float*)d_ws;
    float* loss_acc = ws;            // [0]
    float* counts   = ws + 64;       // [1024]
    float* enorm    = ws + 2048;     // [1024]

    float* out_zq   = (float*)d_out;                       // 16777216
    float* out_idx  = out_zq + (size_t)Npts * Cdim;        // 65536
    float* out_loss = out_idx + Npts;                      // 1
    float* out_perp = out_loss + 1;                        // 1

    hipMemsetAsync(d_ws, 0, 2048 * sizeof(float), stream); // loss + counts
    enorm_kernel<<<NCODES / 256, 256, 0, stream>>>(embed, enorm);
    vq_main<<<Npts / PTS, 256, 0, stream>>>(z, embed, enorm, out_zq, out_idx,
                                            loss_acc, counts);
    vq_final<<<1, 1024, 0, stream>>>(counts, loss_acc, out_loss, out_perp);
}